// Round 3
// baseline (1674.857 us; speedup 1.0000x reference)
//
#include <hip/hip_runtime.h>
#include <hip/hip_bf16.h>
#include <stdint.h>

#define HDIM 128

typedef __attribute__((ext_vector_type(8))) short short8;
typedef __attribute__((ext_vector_type(4))) float f32x4;

__device__ __forceinline__ ushort f2bf(float f) {
  uint u = __float_as_uint(f);
  u = (u + 0x7fffu + ((u >> 16) & 1u)) >> 16;
  return (ushort)u;
}
__device__ __forceinline__ float bflo(uint v) { return __uint_as_float(v << 16); }
__device__ __forceinline__ float bfhi(uint v) { return __uint_as_float(v & 0xffff0000u); }

// ---------------- setup kernels ----------------

__global__ __launch_bounds__(256) void count_kernel(const int* __restrict__ ei,
                                                    int* __restrict__ cnt, int E) {
  int i = blockIdx.x * 256 + threadIdx.x;
  if (i < E) atomicAdd(&cnt[ei[E + i]], 1);  // dst row of edge_index
}

__global__ __launch_bounds__(256) void dis_kernel(const int* __restrict__ cnt,
                                                  float* __restrict__ dis, int N) {
  int i = blockIdx.x * 256 + threadIdx.x;
  if (i < N) dis[i] = rsqrtf((float)(cnt[i] + 1));  // +1 self loop, deg>=1 always
}

// padded degree: rows padded to multiple of 8 edges
__device__ __forceinline__ int pdeg8(int c) { return (c + 8) & ~7; }  // pad8(c+1)

// per-block totals of v[n]=pad8(cnt[n]+1) over 1024-elem tiles
__global__ __launch_bounds__(256) void scan1(const int* __restrict__ cnt,
                                             int* __restrict__ bsum, int N) {
  __shared__ int red[256];
  int b = blockIdx.x, t = threadIdx.x;
  int base = b * 1024;
  int s = 0;
  for (int i = t; i < 1024; i += 256) {
    int n = base + i;
    if (n < N) s += pdeg8(cnt[n]);
  }
  red[t] = s;
  __syncthreads();
  for (int off = 128; off; off >>= 1) {
    if (t < off) red[t] += red[t + off];
    __syncthreads();
  }
  if (t == 0) bsum[b] = red[0];
}

// exclusive scan of nb block sums (nb <= 256)
__global__ __launch_bounds__(256) void scan2(int* __restrict__ bsum, int nb) {
  __shared__ int sh[256];
  int t = threadIdx.x;
  int v = (t < nb) ? bsum[t] : 0;
  sh[t] = v;
  __syncthreads();
  for (int off = 1; off < 256; off <<= 1) {
    int add = (t >= off) ? sh[t - off] : 0;
    __syncthreads();
    sh[t] += add;
    __syncthreads();
  }
  if (t < nb) bsum[t] = sh[t] - v;
}

// per-element exclusive prefix -> row_ptr (N+1 entries, padded) + cursor copy
__global__ __launch_bounds__(256) void scan3(const int* __restrict__ cnt,
                                             const int* __restrict__ bsum,
                                             int* __restrict__ rowptr,
                                             int* __restrict__ cursor, int N) {
  __shared__ int sh[256];
  int b = blockIdx.x, t = threadIdx.x;
  int base = b * 1024 + t * 4;
  int v[4];
#pragma unroll
  for (int i = 0; i < 4; ++i) {
    int n = base + i;
    v[i] = (n < N) ? pdeg8(cnt[n]) : 0;
  }
  int tsum = v[0] + v[1] + v[2] + v[3];
  sh[t] = tsum;
  __syncthreads();
  for (int off = 1; off < 256; off <<= 1) {
    int add = (t >= off) ? sh[t - off] : 0;
    __syncthreads();
    sh[t] += add;
    __syncthreads();
  }
  int p = sh[t] - tsum + bsum[b];
#pragma unroll
  for (int i = 0; i < 4; ++i) {
    int n = base + i;
    if (n <= N) rowptr[n] = p;
    if (n < N) cursor[n] = p;
    p += v[i];
  }
}

// packed entry: src (17 bits) | bf15 weight << 17 (weight in (0,1], sign dropped)
__device__ __forceinline__ uint pack_cw(int src, float w) {
  uint w15 = (__float_as_uint(w) + 0x8000u) >> 16;  // 15 bits (w <= 1.0)
  return (uint)src | (w15 << 17);
}

__global__ __launch_bounds__(256) void fill_csr(const int* __restrict__ ei,
                                                const float* __restrict__ dis,
                                                int* __restrict__ cursor,
                                                uint* __restrict__ colw, int E, int N) {
  int i = blockIdx.x * 256 + threadIdx.x;
  if (i < E) {
    int s = ei[i], d = ei[E + i];
    int pos = atomicAdd(&cursor[d], 1);
    colw[pos] = pack_cw(s, dis[s] * dis[d]);
  } else if (i < E + N) {
    int n = i - E;
    int pos = atomicAdd(&cursor[n], 1);
    colw[pos] = pack_cw(n, dis[n] * dis[n]);
  }
}

// zero-fill pad entries [beg+deg, beg+pdeg)
__global__ __launch_bounds__(256) void pad_csr(const int* __restrict__ cnt,
                                               const int* __restrict__ rowptr,
                                               uint* __restrict__ colw, int N) {
  int n = blockIdx.x * 256 + threadIdx.x;
  if (n >= N) return;
  int beg = rowptr[n] + cnt[n] + 1, end = rowptr[n + 1];
  for (int j = beg; j < end; ++j) colw[j] = 0;  // src 0, w 0
}

// Pre-swizzle Ws into MFMA B-fragment order per layer
__global__ __launch_bounds__(256) void swz_w(const float* __restrict__ Ws,
                                             ushort* __restrict__ Wsw, int total) {
  int idx = blockIdx.x * 256 + threadIdx.x;
  if (idx >= total) return;
  int l = idx >> 14, r = idx & 16383;
  int j = r & 7, lane = (r >> 3) & 63, kk = (r >> 9) & 3, c = r >> 11;
  int n = c * 16 + (lane & 15);
  int k = kk * 32 + (lane >> 4) * 8 + j;
  Wsw[idx] = f2bf(Ws[l * 16384 + k * HDIM + n]);
}

// ---------------- per-layer kernels ----------------
// Activations use slice-major layout: X[s][node][16 cols], s in 0..7.

// XW = X @ W. 64 rows/block, 4 waves x 16 rows. Output slice-major.
template <bool F32IN>
__global__ __launch_bounds__(256) void gemm_kernel(const void* __restrict__ Xin,
                                                   const ushort* __restrict__ Wsw,
                                                   ushort* __restrict__ XW, int N) {
  __shared__ ushort wlds[16384];  // 32 KB: swizzled W; later reused as C tile (stride 136)
  const int t = threadIdx.x;
  {
    const int4* src = (const int4*)Wsw;
    int4* dst = (int4*)wlds;
#pragma unroll
    for (int i = 0; i < 8; ++i) dst[t + 256 * i] = src[t + 256 * i];
  }
  __syncthreads();

  const int wave = t >> 6, lane = t & 63;
  const int kq = lane >> 4;  // 0..3
  const int row0 = blockIdx.x * 64 + wave * 16 + (lane & 15);
  const bool inb = row0 < N;

  short8 afr[4];
#pragma unroll
  for (int kk = 0; kk < 4; ++kk) afr[kk] = short8{0, 0, 0, 0, 0, 0, 0, 0};
  if (inb) {
    if constexpr (F32IN) {
      const float* arow = (const float*)Xin + (size_t)row0 * HDIM;
#pragma unroll
      for (int kk = 0; kk < 4; ++kk) {
        float4 x0 = *(const float4*)(arow + kk * 32 + kq * 8);
        float4 x1 = *(const float4*)(arow + kk * 32 + kq * 8 + 4);
        short8 f;
        f[0] = (short)f2bf(x0.x); f[1] = (short)f2bf(x0.y);
        f[2] = (short)f2bf(x0.z); f[3] = (short)f2bf(x0.w);
        f[4] = (short)f2bf(x1.x); f[5] = (short)f2bf(x1.y);
        f[6] = (short)f2bf(x1.z); f[7] = (short)f2bf(x1.w);
        afr[kk] = f;
      }
    } else {
      const ushort* xsb = (const ushort*)Xin;
#pragma unroll
      for (int kk = 0; kk < 4; ++kk) {
        int slice = kk * 2 + (kq >> 1);
        size_t off = (size_t)slice * N * 16 + (size_t)row0 * 16 + (kq & 1) * 8;
        afr[kk] = *(const short8*)(xsb + off);
      }
    }
  }

  f32x4 acc[8];
#pragma unroll
  for (int c = 0; c < 8; ++c) acc[c] = f32x4{0.f, 0.f, 0.f, 0.f};

#pragma unroll
  for (int kk = 0; kk < 4; ++kk) {
#pragma unroll
    for (int c = 0; c < 8; ++c) {
      short8 bfr = *(const short8*)(wlds + (((c * 4 + kk) * 64 + lane) << 3));
      acc[c] = __builtin_amdgcn_mfma_f32_16x16x32_bf16(afr[kk], bfr, acc[c], 0, 0, 0);
    }
  }

  __syncthreads();  // done reading W; reuse LDS for C tile (stride 136 vs bank conflicts)
  const int m0 = wave * 16 + kq * 4;
#pragma unroll
  for (int c = 0; c < 8; ++c) {
    int col = c * 16 + (lane & 15);
#pragma unroll
    for (int r = 0; r < 4; ++r) wlds[(m0 + r) * 136 + col] = f2bf(acc[c][r]);
  }
  __syncthreads();
  // slice-major store: per slice, 64 rows x 32 B contiguous
  const int idx2 = t & 127, row = idx2 >> 1, half = idx2 & 1;
  const int grow = blockIdx.x * 64 + row;
#pragma unroll
  for (int i = 0; i < 4; ++i) {
    int s = (t >> 7) + 2 * i;
    if (grow < N) {
      int4 val = *(const int4*)(wlds + row * 136 + s * 16 + half * 8);
      ((int4*)XW)[(size_t)s * N * 2 + (size_t)grow * 2 + half] = val;
    }
  }
}

// Sliced aggregation: block handles slice (blockIdx&7), 4 nodes (1/wave).
// lane = e*8+d: e = edge in group of 8, d = dword (2 cols). Gathers stay in the
// XCD-resident 3.2 MB slice; colw streamed nontemporal. Rows padded to x8.
__global__ __launch_bounds__(256) void agg_slice(const ushort* __restrict__ XW,
                                                 const uint* __restrict__ colw,
                                                 const int* __restrict__ rowptr,
                                                 const float* __restrict__ bias,
                                                 ushort* __restrict__ Y, int N) {
  const int lane = threadIdx.x & 63;
  const int s = blockIdx.x & 7;
  const int node = (blockIdx.x >> 3) * 4 + (threadIdx.x >> 6);
  if (node >= N) return;
  const int e = lane >> 3, d = lane & 7;
  const int beg = rowptr[node];
  const int last = ((rowptr[node + 1] - beg) >> 3) - 1;  // >= 0 (deg >= 1)
  const ushort* xs = XW + (size_t)s * N * 16;
  const int dd = d << 1;  // ushort offset within row-slice
  const uint* cw = colw + beg + e;

  uint u_cur = __builtin_nontemporal_load(cw);
  uint u_nxt = __builtin_nontemporal_load(cw + (last ? 8 : 0));
  uint src = u_cur & 0x1FFFFu;
  float w = __uint_as_float((u_cur >> 17) << 16);
  uint v_cur = *(const uint*)(xs + (src << 4) + dd);
  float a0 = 0.f, a1 = 0.f;
  for (int it = 1; it <= last; ++it) {
    int pre = it < last ? it + 1 : last;
    uint u_pre = __builtin_nontemporal_load(cw + pre * 8);
    uint srcn = u_nxt & 0x1FFFFu;
    float wn = __uint_as_float((u_nxt >> 17) << 16);
    uint v_nxt = *(const uint*)(xs + (srcn << 4) + dd);
    a0 += w * bflo(v_cur);
    a1 += w * bfhi(v_cur);
    v_cur = v_nxt;
    w = wn;
    u_nxt = u_pre;
  }
  a0 += w * bflo(v_cur);
  a1 += w * bfhi(v_cur);
  // reduce over e (lanes differing in bits 3..5)
  a0 += __shfl_xor(a0, 8, 64);
  a1 += __shfl_xor(a1, 8, 64);
  a0 += __shfl_xor(a0, 16, 64);
  a1 += __shfl_xor(a1, 16, 64);
  a0 += __shfl_xor(a0, 32, 64);
  a1 += __shfl_xor(a1, 32, 64);
  if (e == 0) {
    float2 bv = *(const float2*)(bias + s * 16 + d * 2);
    float r0 = fmaxf(a0 + bv.x, 0.f);
    float r1 = fmaxf(a1 + bv.y, 0.f);
    uint pk = (uint)f2bf(r0) | ((uint)f2bf(r1) << 16);
    *((uint*)Y + (size_t)s * N * 8 + (size_t)node * 8 + d) = pk;
  }
}

// ---------------- pooling + head ----------------

__global__ __launch_bounds__(256) void pool_partial(const ushort* __restrict__ x,
                                                    const int* __restrict__ batch,
                                                    float* __restrict__ pooled,
                                                    int* __restrict__ gcnt, int N) {
  const int g = blockIdx.x, s = blockIdx.y;  // gridDim.y = 8 splits
  const int t = threadIdx.x;
  __shared__ int range[2];
  __shared__ float sums[256];
  if (t < 2) {
    int target = g + t;
    int lo = 0, hi = N;
    while (lo < hi) {
      int mid = (lo + hi) >> 1;
      if (batch[mid] < target) lo = mid + 1;
      else hi = mid;
    }
    range[t] = lo;
  }
  __syncthreads();
  int beg = range[0], end = range[1];
  if (s == 0 && t == 0) gcnt[g] = end - beg;
  int col = t & 127, half = t >> 7;
  const ushort* xp = x + (size_t)(col >> 4) * N * 16 + (col & 15);
  float acc = 0.f;
  for (int n = beg + s * 2 + half; n < end; n += 16) {
    acc += __uint_as_float(((uint)xp[(size_t)n * 16]) << 16);
  }
  sums[t] = acc;
  __syncthreads();
  if (t < 128) atomicAdd(&pooled[g * HDIM + t], sums[t] + sums[t + 128]);
}

__global__ __launch_bounds__(256) void out_final(const float* __restrict__ pooled,
                                                 const int* __restrict__ gcnt,
                                                 const float* __restrict__ W_out,
                                                 const float* __restrict__ b_out,
                                                 float* __restrict__ out, int G, int C) {
  int i = blockIdx.x * 256 + threadIdx.x;
  if (i >= G * C) return;
  int g = i / C, c = i - g * C;
  float inv = 1.f / (float)max(gcnt[g], 1);
  const float* pg = pooled + g * HDIM;
  float o = 0.f;
  for (int h = 0; h < HDIM; ++h) o += pg[h] * W_out[h * C + c];
  out[i] = b_out[c] + o * inv;
}

// ---------------- host ----------------

extern "C" void kernel_launch(void* const* d_in, const int* in_sizes, int n_in,
                              void* d_out, int out_size, void* d_ws, size_t ws_size,
                              hipStream_t stream) {
  (void)n_in;
  (void)ws_size;
  const float* x = (const float*)d_in[0];
  const int* ei = (const int*)d_in[1];
  const int* batch = (const int*)d_in[2];
  const float* Ws = (const float*)d_in[4];
  const float* bs = (const float*)d_in[5];
  const float* W_out = (const float*)d_in[6];
  const float* b_out = (const float*)d_in[7];
  float* out = (float*)d_out;

  const int N = in_sizes[0] / HDIM;
  const int E = in_sizes[1] / 2;
  const int L = in_sizes[5] / HDIM;
  const int C = in_sizes[7];
  const int G = out_size / C;

  char* p = (char*)d_ws;
  auto carve = [&](size_t bytes) {
    char* r = p;
    p += (bytes + 255) & ~(size_t)255;
    return r;
  };
  int* cnt = (int*)carve((size_t)N * 4);
  float* dis = (float*)carve((size_t)N * 4);
  int* rowptr = (int*)carve((size_t)(N + 1) * 4);
  int* cursor = (int*)carve((size_t)N * 4);
  int* bsum = (int*)carve(4096);
  uint* colw = (uint*)carve(((size_t)E + 8 * (size_t)N) * 4);
  ushort* Wsw = (ushort*)carve((size_t)L * HDIM * HDIM * 2);
  ushort* xw = (ushort*)carve((size_t)N * HDIM * 2);
  ushort* y0 = (ushort*)carve((size_t)N * HDIM * 2);
  ushort* y1 = (ushort*)carve((size_t)N * HDIM * 2);
  float* pooled = (float*)carve((size_t)G * HDIM * 4 + (size_t)G * 4);
  int* gcnt = (int*)(pooled + (size_t)G * HDIM);

  hipMemsetAsync(cnt, 0, (size_t)N * 4, stream);
  hipMemsetAsync(pooled, 0, (size_t)G * HDIM * 4 + (size_t)G * 4, stream);

  count_kernel<<<(E + 255) / 256, 256, 0, stream>>>(ei, cnt, E);
  dis_kernel<<<(N + 255) / 256, 256, 0, stream>>>(cnt, dis, N);
  int nb = (N + 1 + 1023) / 1024;
  scan1<<<nb, 256, 0, stream>>>(cnt, bsum, N);
  scan2<<<1, 256, 0, stream>>>(bsum, nb);
  scan3<<<nb, 256, 0, stream>>>(cnt, bsum, rowptr, cursor, N);
  fill_csr<<<(E + N + 255) / 256, 256, 0, stream>>>(ei, dis, cursor, colw, E, N);
  pad_csr<<<(N + 255) / 256, 256, 0, stream>>>(cnt, rowptr, colw, N);
  swz_w<<<(L * HDIM * HDIM + 255) / 256, 256, 0, stream>>>(Ws, Wsw, L * HDIM * HDIM);

  const int gb = (N + 63) / 64;
  const int ab = ((N + 3) / 4) * 8;  // 8 slices; slice = blockIdx & 7 -> XCD round-robin
  gemm_kernel<true><<<gb, 256, 0, stream>>>(x, Wsw, xw, N);
  agg_slice<<<ab, 256, 0, stream>>>(xw, colw, rowptr, bs, y0, N);
  ushort* xc = y0;
  ushort* xn = y1;
  for (int l = 1; l < L; ++l) {
    gemm_kernel<false><<<gb, 256, 0, stream>>>(xc, Wsw + (size_t)l * HDIM * HDIM, xw, N);
    agg_slice<<<ab, 256, 0, stream>>>(xw, colw, rowptr, bs + (size_t)l * HDIM, xn, N);
    ushort* tmp = xc;
    xc = xn;
    xn = tmp;
  }
  pool_partial<<<dim3(G, 8), 256, 0, stream>>>(xc, batch, pooled, gcnt, N);
  out_final<<<(G * C + 255) / 256, 256, 0, stream>>>(pooled, gcnt, W_out, b_out, out, G, C);
}

// Round 4
// 1618.234 us; speedup vs baseline: 1.0350x; 1.0350x over previous
//
#include <hip/hip_runtime.h>
#include <hip/hip_bf16.h>
#include <stdint.h>

#define HDIM 128

typedef __attribute__((ext_vector_type(8))) short short8;
typedef __attribute__((ext_vector_type(4))) float f32x4;

__device__ __forceinline__ ushort f2bf(float f) {
  uint u = __float_as_uint(f);
  u = (u + 0x7fffu + ((u >> 16) & 1u)) >> 16;
  return (ushort)u;
}
__device__ __forceinline__ float bflo(uint v) { return __uint_as_float(v << 16); }
__device__ __forceinline__ float bfhi(uint v) { return __uint_as_float(v & 0xffff0000u); }

// ---------------- setup kernels ----------------

__global__ __launch_bounds__(256) void count_kernel(const int* __restrict__ ei,
                                                    int* __restrict__ cnt, int E) {
  int i = blockIdx.x * 256 + threadIdx.x;
  if (i < E) atomicAdd(&cnt[ei[E + i]], 1);  // dst row of edge_index
}

__global__ __launch_bounds__(256) void dis_kernel(const int* __restrict__ cnt,
                                                  float* __restrict__ dis, int N) {
  int i = blockIdx.x * 256 + threadIdx.x;
  if (i < N) dis[i] = rsqrtf((float)(cnt[i] + 1));  // +1 self loop, deg>=1 always
}

// padded degree: rows padded to multiple of 8 edges
__device__ __forceinline__ int pdeg8(int c) { return (c + 8) & ~7; }  // pad8(c+1)

__global__ __launch_bounds__(256) void scan1(const int* __restrict__ cnt,
                                             int* __restrict__ bsum, int N) {
  __shared__ int red[256];
  int b = blockIdx.x, t = threadIdx.x;
  int base = b * 1024;
  int s = 0;
  for (int i = t; i < 1024; i += 256) {
    int n = base + i;
    if (n < N) s += pdeg8(cnt[n]);
  }
  red[t] = s;
  __syncthreads();
  for (int off = 128; off; off >>= 1) {
    if (t < off) red[t] += red[t + off];
    __syncthreads();
  }
  if (t == 0) bsum[b] = red[0];
}

__global__ __launch_bounds__(256) void scan2(int* __restrict__ bsum, int nb) {
  __shared__ int sh[256];
  int t = threadIdx.x;
  int v = (t < nb) ? bsum[t] : 0;
  sh[t] = v;
  __syncthreads();
  for (int off = 1; off < 256; off <<= 1) {
    int add = (t >= off) ? sh[t - off] : 0;
    __syncthreads();
    sh[t] += add;
    __syncthreads();
  }
  if (t < nb) bsum[t] = sh[t] - v;
}

__global__ __launch_bounds__(256) void scan3(const int* __restrict__ cnt,
                                             const int* __restrict__ bsum,
                                             int* __restrict__ rowptr,
                                             int* __restrict__ cursor, int N) {
  __shared__ int sh[256];
  int b = blockIdx.x, t = threadIdx.x;
  int base = b * 1024 + t * 4;
  int v[4];
#pragma unroll
  for (int i = 0; i < 4; ++i) {
    int n = base + i;
    v[i] = (n < N) ? pdeg8(cnt[n]) : 0;
  }
  int tsum = v[0] + v[1] + v[2] + v[3];
  sh[t] = tsum;
  __syncthreads();
  for (int off = 1; off < 256; off <<= 1) {
    int add = (t >= off) ? sh[t - off] : 0;
    __syncthreads();
    sh[t] += add;
    __syncthreads();
  }
  int p = sh[t] - tsum + bsum[b];
#pragma unroll
  for (int i = 0; i < 4; ++i) {
    int n = base + i;
    if (n <= N) rowptr[n] = p;
    if (n < N) cursor[n] = p;
    p += v[i];
  }
}

// packed entry: src (17 bits) | bf15 weight << 17 (weight in (0,1], sign dropped)
__device__ __forceinline__ uint pack_cw(int src, float w) {
  uint w15 = (__float_as_uint(w) + 0x8000u) >> 16;  // 15 bits (w <= 1.0)
  return (uint)src | (w15 << 17);
}

__global__ __launch_bounds__(256) void fill_csr(const int* __restrict__ ei,
                                                const float* __restrict__ dis,
                                                int* __restrict__ cursor,
                                                uint* __restrict__ colw, int E, int N) {
  int i = blockIdx.x * 256 + threadIdx.x;
  if (i < E) {
    int s = ei[i], d = ei[E + i];
    int pos = atomicAdd(&cursor[d], 1);
    colw[pos] = pack_cw(s, dis[s] * dis[d]);
  } else if (i < E + N) {
    int n = i - E;
    int pos = atomicAdd(&cursor[n], 1);
    colw[pos] = pack_cw(n, dis[n] * dis[n]);
  }
}

// zero-fill pad entries [beg+deg, beg+pdeg)
__global__ __launch_bounds__(256) void pad_csr(const int* __restrict__ cnt,
                                               const int* __restrict__ rowptr,
                                               uint* __restrict__ colw, int N) {
  int n = blockIdx.x * 256 + threadIdx.x;
  if (n >= N) return;
  int beg = rowptr[n] + cnt[n] + 1, end = rowptr[n + 1];
  for (int j = beg; j < end; ++j) colw[j] = 0;  // src 0, w 0
}

// Pre-swizzle Ws into MFMA B-fragment order per layer
__global__ __launch_bounds__(256) void swz_w(const float* __restrict__ Ws,
                                             ushort* __restrict__ Wsw, int total) {
  int idx = blockIdx.x * 256 + threadIdx.x;
  if (idx >= total) return;
  int l = idx >> 14, r = idx & 16383;
  int j = r & 7, lane = (r >> 3) & 63, kk = (r >> 9) & 3, c = r >> 11;
  int n = c * 16 + (lane & 15);
  int k = kk * 32 + (lane >> 4) * 8 + j;
  Wsw[idx] = f2bf(Ws[l * 16384 + k * HDIM + n]);
}

// ---------------- per-layer kernels ----------------
// Activations use slice-major layout: X[s][node][16 cols], s in 0..7.

// XW = X @ W. 64 rows/block, 4 waves x 16 rows. Output slice-major.
template <bool F32IN>
__global__ __launch_bounds__(256) void gemm_kernel(const void* __restrict__ Xin,
                                                   const ushort* __restrict__ Wsw,
                                                   ushort* __restrict__ XW, int N) {
  __shared__ ushort wlds[16384];  // 32 KB: swizzled W; later reused as C tile (stride 136)
  const int t = threadIdx.x;
  {
    const int4* src = (const int4*)Wsw;
    int4* dst = (int4*)wlds;
#pragma unroll
    for (int i = 0; i < 8; ++i) dst[t + 256 * i] = src[t + 256 * i];
  }
  __syncthreads();

  const int wave = t >> 6, lane = t & 63;
  const int kq = lane >> 4;  // 0..3
  const int row0 = blockIdx.x * 64 + wave * 16 + (lane & 15);
  const bool inb = row0 < N;

  short8 afr[4];
#pragma unroll
  for (int kk = 0; kk < 4; ++kk) afr[kk] = short8{0, 0, 0, 0, 0, 0, 0, 0};
  if (inb) {
    if constexpr (F32IN) {
      const float* arow = (const float*)Xin + (size_t)row0 * HDIM;
#pragma unroll
      for (int kk = 0; kk < 4; ++kk) {
        float4 x0 = *(const float4*)(arow + kk * 32 + kq * 8);
        float4 x1 = *(const float4*)(arow + kk * 32 + kq * 8 + 4);
        short8 f;
        f[0] = (short)f2bf(x0.x); f[1] = (short)f2bf(x0.y);
        f[2] = (short)f2bf(x0.z); f[3] = (short)f2bf(x0.w);
        f[4] = (short)f2bf(x1.x); f[5] = (short)f2bf(x1.y);
        f[6] = (short)f2bf(x1.z); f[7] = (short)f2bf(x1.w);
        afr[kk] = f;
      }
    } else {
      const ushort* xsb = (const ushort*)Xin;
#pragma unroll
      for (int kk = 0; kk < 4; ++kk) {
        int slice = kk * 2 + (kq >> 1);
        size_t off = (size_t)slice * N * 16 + (size_t)row0 * 16 + (kq & 1) * 8;
        afr[kk] = *(const short8*)(xsb + off);
      }
    }
  }

  f32x4 acc[8];
#pragma unroll
  for (int c = 0; c < 8; ++c) acc[c] = f32x4{0.f, 0.f, 0.f, 0.f};

#pragma unroll
  for (int kk = 0; kk < 4; ++kk) {
#pragma unroll
    for (int c = 0; c < 8; ++c) {
      short8 bfr = *(const short8*)(wlds + (((c * 4 + kk) * 64 + lane) << 3));
      acc[c] = __builtin_amdgcn_mfma_f32_16x16x32_bf16(afr[kk], bfr, acc[c], 0, 0, 0);
    }
  }

  __syncthreads();  // done reading W; reuse LDS for C tile (stride 136 vs bank conflicts)
  const int m0 = wave * 16 + kq * 4;
#pragma unroll
  for (int c = 0; c < 8; ++c) {
    int col = c * 16 + (lane & 15);
#pragma unroll
    for (int r = 0; r < 4; ++r) wlds[(m0 + r) * 136 + col] = f2bf(acc[c][r]);
  }
  __syncthreads();
  // slice-major store: per slice, 64 rows x 32 B contiguous
  const int idx2 = t & 127, row = idx2 >> 1, half = idx2 & 1;
  const int grow = blockIdx.x * 64 + row;
#pragma unroll
  for (int i = 0; i < 4; ++i) {
    int s = (t >> 7) + 2 * i;
    if (grow < N) {
      int4 val = *(const int4*)(wlds + row * 136 + s * 16 + half * 8);
      ((int4*)XW)[(size_t)s * N * 2 + (size_t)grow * 2 + half] = val;
    }
  }
}

// Streaming sliced aggregation. slice = blockIdx&7 (XCD round-robin; slice data
// 3.2MB stays L2-resident). 8192 waves per slice; each wave owns a contiguous,
// node-aligned ~gpw*8-edge range of the padded CSR and streams 8-edge groups
// with unroll-2 pipelining (2 gathers in flight, colw prefetched 2 groups ahead).
// lane = e*8+d: e = edge in group, d = dword (2 cols of the 16-col slice).
__global__ __launch_bounds__(256) void agg_stream(const ushort* __restrict__ XW,
                                                  const uint* __restrict__ colw,
                                                  const int* __restrict__ rowptr,
                                                  const float* __restrict__ bias,
                                                  ushort* __restrict__ Y, int N) {
  const int lane = threadIdx.x & 63;
  const int e = lane >> 3, d = lane & 7;
  const int s = blockIdx.x & 7;
  const int w = (blockIdx.x >> 3) * 4 + (threadIdx.x >> 6);  // 0..8191
  const int Epad = rowptr[N];
  const int gpw = (Epad + 65535) >> 16;  // ceil(Epad/8/8192) groups per wave
  const int e0 = w * (gpw << 3);
  if (e0 >= Epad) return;
  const int e1 = min(Epad, e0 + (gpw << 3));

  // first node with row start >= e0 / >= e1 (wave-uniform binary searches)
  int lo = 0, hi = N;
  while (lo < hi) {
    int m = (lo + hi) >> 1;
    if (rowptr[m] < e0) lo = m + 1;
    else hi = m;
  }
  const int nstart = lo;
  hi = N;
  while (lo < hi) {
    int m = (lo + hi) >> 1;
    if (rowptr[m] < e1) lo = m + 1;
    else hi = m;
  }
  const int nend = lo;
  if (nstart >= nend) return;

  const ushort* xs = XW + (size_t)s * N * 16;
  const int dd = d << 1;
  uint* yout = (uint*)Y + (size_t)s * N * 8 + d;
  const float2 bv = *(const float2*)(bias + s * 16 + dd);

  int n = nstart;
  const int ebeg = rowptr[nstart], eend = rowptr[nend];
  int r = (rowptr[n + 1] - ebeg) >> 3;  // groups remaining in current node
  float a0 = 0.f, a1 = 0.f;

  auto flush = [&]() {
    a0 += __shfl_xor(a0, 8, 64);
    a1 += __shfl_xor(a1, 8, 64);
    a0 += __shfl_xor(a0, 16, 64);
    a1 += __shfl_xor(a1, 16, 64);
    a0 += __shfl_xor(a0, 32, 64);
    a1 += __shfl_xor(a1, 32, 64);
    if (e == 0) {
      float r0 = fmaxf(a0 + bv.x, 0.f);
      float r1 = fmaxf(a1 + bv.y, 0.f);
      yout[(size_t)n * 8] = (uint)f2bf(r0) | ((uint)f2bf(r1) << 16);
    }
    ++n;
    if (n < nend) r = (rowptr[n + 1] - rowptr[n]) >> 3;
    a0 = 0.f;
    a1 = 0.f;
  };

  int j = ebeg;
  uint uA = __builtin_nontemporal_load(colw + j + e);
  uint uB = __builtin_nontemporal_load(colw + j + 8 + e);
  while (j < eend) {
    const bool hasB = (j + 8) < eend;
    uint uA2 = __builtin_nontemporal_load(colw + j + 16 + e);
    uint uB2 = __builtin_nontemporal_load(colw + j + 24 + e);
    uint sA = uA & 0x1FFFFu;
    float wA = __uint_as_float((uA >> 17) << 16);
    uint vA = *(const uint*)(xs + (sA << 4) + dd);
    uint uBg = hasB ? uB : 0u;
    uint sB = uBg & 0x1FFFFu;
    float wB = __uint_as_float((uBg >> 17) << 16);
    uint vB = *(const uint*)(xs + (sB << 4) + dd);
    a0 += wA * bflo(vA);
    a1 += wA * bfhi(vA);
    if (--r == 0) flush();
    if (hasB) {
      a0 += wB * bflo(vB);
      a1 += wB * bfhi(vB);
      if (--r == 0) flush();
    }
    uA = uA2;
    uB = uB2;
    j += 16;
  }
}

// ---------------- pooling + head ----------------

__global__ __launch_bounds__(256) void pool_partial(const ushort* __restrict__ x,
                                                    const int* __restrict__ batch,
                                                    float* __restrict__ pooled,
                                                    int* __restrict__ gcnt, int N) {
  const int g = blockIdx.x, s = blockIdx.y;  // gridDim.y = 8 splits
  const int t = threadIdx.x;
  __shared__ int range[2];
  __shared__ float sums[256];
  if (t < 2) {
    int target = g + t;
    int lo = 0, hi = N;
    while (lo < hi) {
      int mid = (lo + hi) >> 1;
      if (batch[mid] < target) lo = mid + 1;
      else hi = mid;
    }
    range[t] = lo;
  }
  __syncthreads();
  int beg = range[0], end = range[1];
  if (s == 0 && t == 0) gcnt[g] = end - beg;
  int col = t & 127, half = t >> 7;
  const ushort* xp = x + (size_t)(col >> 4) * N * 16 + (col & 15);
  float acc = 0.f;
  for (int n = beg + s * 2 + half; n < end; n += 16) {
    acc += __uint_as_float(((uint)xp[(size_t)n * 16]) << 16);
  }
  sums[t] = acc;
  __syncthreads();
  if (t < 128) atomicAdd(&pooled[g * HDIM + t], sums[t] + sums[t + 128]);
}

__global__ __launch_bounds__(256) void out_final(const float* __restrict__ pooled,
                                                 const int* __restrict__ gcnt,
                                                 const float* __restrict__ W_out,
                                                 const float* __restrict__ b_out,
                                                 float* __restrict__ out, int G, int C) {
  int i = blockIdx.x * 256 + threadIdx.x;
  if (i >= G * C) return;
  int g = i / C, c = i - g * C;
  float inv = 1.f / (float)max(gcnt[g], 1);
  const float* pg = pooled + g * HDIM;
  float o = 0.f;
  for (int h = 0; h < HDIM; ++h) o += pg[h] * W_out[h * C + c];
  out[i] = b_out[c] + o * inv;
}

// ---------------- host ----------------

extern "C" void kernel_launch(void* const* d_in, const int* in_sizes, int n_in,
                              void* d_out, int out_size, void* d_ws, size_t ws_size,
                              hipStream_t stream) {
  (void)n_in;
  (void)ws_size;
  const float* x = (const float*)d_in[0];
  const int* ei = (const int*)d_in[1];
  const int* batch = (const int*)d_in[2];
  const float* Ws = (const float*)d_in[4];
  const float* bs = (const float*)d_in[5];
  const float* W_out = (const float*)d_in[6];
  const float* b_out = (const float*)d_in[7];
  float* out = (float*)d_out;

  const int N = in_sizes[0] / HDIM;
  const int E = in_sizes[1] / 2;
  const int L = in_sizes[5] / HDIM;
  const int C = in_sizes[7];
  const int G = out_size / C;

  char* p = (char*)d_ws;
  auto carve = [&](size_t bytes) {
    char* r = p;
    p += (bytes + 255) & ~(size_t)255;
    return r;
  };
  int* cnt = (int*)carve((size_t)N * 4);
  float* dis = (float*)carve((size_t)N * 4);
  int* rowptr = (int*)carve((size_t)(N + 1) * 4);
  int* cursor = (int*)carve((size_t)N * 4);
  int* bsum = (int*)carve(4096);
  uint* colw = (uint*)carve(((size_t)E + 8 * (size_t)N + 64) * 4);  // +64 prefetch slack
  ushort* Wsw = (ushort*)carve((size_t)L * HDIM * HDIM * 2);
  ushort* xw = (ushort*)carve((size_t)N * HDIM * 2);
  ushort* y0 = (ushort*)carve((size_t)N * HDIM * 2);
  ushort* y1 = (ushort*)carve((size_t)N * HDIM * 2);
  float* pooled = (float*)carve((size_t)G * HDIM * 4 + (size_t)G * 4);
  int* gcnt = (int*)(pooled + (size_t)G * HDIM);

  hipMemsetAsync(cnt, 0, (size_t)N * 4, stream);
  hipMemsetAsync(pooled, 0, (size_t)G * HDIM * 4 + (size_t)G * 4, stream);

  count_kernel<<<(E + 255) / 256, 256, 0, stream>>>(ei, cnt, E);
  dis_kernel<<<(N + 255) / 256, 256, 0, stream>>>(cnt, dis, N);
  int nb = (N + 1 + 1023) / 1024;
  scan1<<<nb, 256, 0, stream>>>(cnt, bsum, N);
  scan2<<<1, 256, 0, stream>>>(bsum, nb);
  scan3<<<nb, 256, 0, stream>>>(cnt, bsum, rowptr, cursor, N);
  fill_csr<<<(E + N + 255) / 256, 256, 0, stream>>>(ei, dis, cursor, colw, E, N);
  pad_csr<<<(N + 255) / 256, 256, 0, stream>>>(cnt, rowptr, colw, N);
  swz_w<<<(L * HDIM * HDIM + 255) / 256, 256, 0, stream>>>(Ws, Wsw, L * HDIM * HDIM);

  const int gb = (N + 63) / 64;
  const int ab = 8 * 2048;  // 8 slices x 2048 blocks (4 waves) = 8192 waves/slice
  gemm_kernel<true><<<gb, 256, 0, stream>>>(x, Wsw, xw, N);
  agg_stream<<<ab, 256, 0, stream>>>(xw, colw, rowptr, bs, y0, N);
  ushort* xc = y0;
  ushort* xn = y1;
  for (int l = 1; l < L; ++l) {
    gemm_kernel<false><<<gb, 256, 0, stream>>>(xc, Wsw + (size_t)l * HDIM * HDIM, xw, N);
    agg_stream<<<ab, 256, 0, stream>>>(xw, colw, rowptr, bs + (size_t)l * HDIM, xn, N);
    ushort* tmp = xc;
    xc = xn;
    xn = tmp;
  }
  pool_partial<<<dim3(G, 8), 256, 0, stream>>>(xc, batch, pooled, gcnt, N);
  out_final<<<(G * C + 255) / 256, 256, 0, stream>>>(pooled, gcnt, W_out, b_out, out, G, C);
}

// Round 5
// 632.828 us; speedup vs baseline: 2.6466x; 2.5571x over previous
//
#include <hip/hip_runtime.h>
#include <hip/hip_bf16.h>
#include <stdint.h>

#define HDIM 128

typedef __attribute__((ext_vector_type(8))) short short8;
typedef __attribute__((ext_vector_type(4))) float f32x4;

__device__ __forceinline__ ushort f2bf(float f) {
  uint u = __float_as_uint(f);
  u = (u + 0x7fffu + ((u >> 16) & 1u)) >> 16;
  return (ushort)u;
}
__device__ __forceinline__ float bflo(uint v) { return __uint_as_float(v << 16); }
__device__ __forceinline__ float bfhi(uint v) { return __uint_as_float(v & 0xffff0000u); }

// ---------------- setup kernels ----------------

__global__ __launch_bounds__(256) void count_kernel(const int* __restrict__ ei,
                                                    int* __restrict__ cnt, int E) {
  int i = blockIdx.x * 256 + threadIdx.x;
  if (i < E) atomicAdd(&cnt[ei[E + i]], 1);  // dst row of edge_index
}

__global__ __launch_bounds__(256) void dis_kernel(const int* __restrict__ cnt,
                                                  float* __restrict__ dis, int N) {
  int i = blockIdx.x * 256 + threadIdx.x;
  if (i < N) dis[i] = rsqrtf((float)(cnt[i] + 1));  // +1 self loop, deg>=1 always
}

// padded degree: deg = cnt+1 padded to multiple of 4
__device__ __forceinline__ int pdeg4(int c) { return (c + 4) & ~3; }

__global__ __launch_bounds__(256) void scan1(const int* __restrict__ cnt,
                                             int* __restrict__ bsum, int N) {
  __shared__ int red[256];
  int b = blockIdx.x, t = threadIdx.x;
  int base = b * 1024;
  int s = 0;
  for (int i = t; i < 1024; i += 256) {
    int n = base + i;
    if (n < N) s += pdeg4(cnt[n]);
  }
  red[t] = s;
  __syncthreads();
  for (int off = 128; off; off >>= 1) {
    if (t < off) red[t] += red[t + off];
    __syncthreads();
  }
  if (t == 0) bsum[b] = red[0];
}

__global__ __launch_bounds__(256) void scan2(int* __restrict__ bsum, int nb) {
  __shared__ int sh[256];
  int t = threadIdx.x;
  int v = (t < nb) ? bsum[t] : 0;
  sh[t] = v;
  __syncthreads();
  for (int off = 1; off < 256; off <<= 1) {
    int add = (t >= off) ? sh[t - off] : 0;
    __syncthreads();
    sh[t] += add;
    __syncthreads();
  }
  if (t < nb) bsum[t] = sh[t] - v;
}

__global__ __launch_bounds__(256) void scan3(const int* __restrict__ cnt,
                                             const int* __restrict__ bsum,
                                             int* __restrict__ rowptr,
                                             int* __restrict__ cursor, int N) {
  __shared__ int sh[256];
  int b = blockIdx.x, t = threadIdx.x;
  int base = b * 1024 + t * 4;
  int v[4];
#pragma unroll
  for (int i = 0; i < 4; ++i) {
    int n = base + i;
    v[i] = (n < N) ? pdeg4(cnt[n]) : 0;
  }
  int tsum = v[0] + v[1] + v[2] + v[3];
  sh[t] = tsum;
  __syncthreads();
  for (int off = 1; off < 256; off <<= 1) {
    int add = (t >= off) ? sh[t - off] : 0;
    __syncthreads();
    sh[t] += add;
    __syncthreads();
  }
  int p = sh[t] - tsum + bsum[b];
#pragma unroll
  for (int i = 0; i < 4; ++i) {
    int n = base + i;
    if (n <= N) rowptr[n] = p;
    if (n < N) cursor[n] = p;
    p += v[i];
  }
}

// packed entry: src (17 bits) | bf15 weight << 17 (weight in (0,1], sign dropped)
__device__ __forceinline__ uint pack_cw(int src, float w) {
  uint w15 = (__float_as_uint(w) + 0x8000u) >> 16;  // 15 bits (w <= 1.0)
  return (uint)src | (w15 << 17);
}
__device__ __forceinline__ uint cw_src(uint u) { return u & 0x1FFFFu; }
__device__ __forceinline__ float cw_w(uint u) { return __uint_as_float((u >> 17) << 16); }

__global__ __launch_bounds__(256) void fill_csr(const int* __restrict__ ei,
                                                const float* __restrict__ dis,
                                                int* __restrict__ cursor,
                                                uint* __restrict__ colw, int E, int N) {
  int i = blockIdx.x * 256 + threadIdx.x;
  if (i < E) {
    int s = ei[i], d = ei[E + i];
    int pos = atomicAdd(&cursor[d], 1);
    colw[pos] = pack_cw(s, dis[s] * dis[d]);
  } else if (i < E + N) {
    int n = i - E;
    int pos = atomicAdd(&cursor[n], 1);
    colw[pos] = pack_cw(n, dis[n] * dis[n]);
  }
}

// zero-weight pads pointing at own row (hot in cache)
__global__ __launch_bounds__(256) void pad_csr(const int* __restrict__ cnt,
                                               const int* __restrict__ rowptr,
                                               uint* __restrict__ colw, int N) {
  int n = blockIdx.x * 256 + threadIdx.x;
  if (n >= N) return;
  int beg = rowptr[n] + cnt[n] + 1, end = rowptr[n + 1];
  for (int j = beg; j < end; ++j) colw[j] = (uint)n;  // src n, w 0
}

// Pre-swizzle Ws into MFMA B-fragment order per layer
__global__ __launch_bounds__(256) void swz_w(const float* __restrict__ Ws,
                                             ushort* __restrict__ Wsw, int total) {
  int idx = blockIdx.x * 256 + threadIdx.x;
  if (idx >= total) return;
  int l = idx >> 14, r = idx & 16383;
  int j = r & 7, lane = (r >> 3) & 63, kk = (r >> 9) & 3, c = r >> 11;
  int n = c * 16 + (lane & 15);
  int k = kk * 32 + (lane >> 4) * 8 + j;
  Wsw[idx] = f2bf(Ws[l * 16384 + k * HDIM + n]);
}

// ---------------- per-layer kernels (row-major activations) ----------------

// XW = X @ W. Persistent: W staged in LDS once, grid-stride over 64-row tiles.
template <bool F32IN>
__global__ __launch_bounds__(256) void gemm_kernel(const void* __restrict__ Xin,
                                                   const ushort* __restrict__ Wsw,
                                                   ushort* __restrict__ XW, int N,
                                                   int ntiles) {
  __shared__ ushort wlds[16384];    // 32 KB swizzled W (persistent)
  __shared__ ushort clds[64 * 136]; // C restage, padded stride
  const int t = threadIdx.x;
  {
    const int4* src = (const int4*)Wsw;
    int4* dst = (int4*)wlds;
#pragma unroll
    for (int i = 0; i < 8; ++i) dst[t + 256 * i] = src[t + 256 * i];
  }
  __syncthreads();

  const int wave = t >> 6, lane = t & 63;
  const int kq = lane >> 4;  // 0..3

  for (int tile = blockIdx.x; tile < ntiles; tile += gridDim.x) {
    const int row0 = tile * 64 + wave * 16 + (lane & 15);
    const bool inb = row0 < N;

    short8 afr[4];
#pragma unroll
    for (int kk = 0; kk < 4; ++kk) afr[kk] = short8{0, 0, 0, 0, 0, 0, 0, 0};
    if (inb) {
      if constexpr (F32IN) {
        const float* arow = (const float*)Xin + (size_t)row0 * HDIM;
#pragma unroll
        for (int kk = 0; kk < 4; ++kk) {
          float4 x0 = *(const float4*)(arow + kk * 32 + kq * 8);
          float4 x1 = *(const float4*)(arow + kk * 32 + kq * 8 + 4);
          short8 f;
          f[0] = (short)f2bf(x0.x); f[1] = (short)f2bf(x0.y);
          f[2] = (short)f2bf(x0.z); f[3] = (short)f2bf(x0.w);
          f[4] = (short)f2bf(x1.x); f[5] = (short)f2bf(x1.y);
          f[6] = (short)f2bf(x1.z); f[7] = (short)f2bf(x1.w);
          afr[kk] = f;
        }
      } else {
        const short8* arow = (const short8*)((const ushort*)Xin + (size_t)row0 * HDIM);
#pragma unroll
        for (int kk = 0; kk < 4; ++kk) afr[kk] = arow[kk * 4 + kq];
      }
    }

    f32x4 acc[8];
#pragma unroll
    for (int c = 0; c < 8; ++c) acc[c] = f32x4{0.f, 0.f, 0.f, 0.f};
#pragma unroll
    for (int kk = 0; kk < 4; ++kk) {
#pragma unroll
      for (int c = 0; c < 8; ++c) {
        short8 bfr = *(const short8*)(wlds + (((c * 4 + kk) * 64 + lane) << 3));
        acc[c] = __builtin_amdgcn_mfma_f32_16x16x32_bf16(afr[kk], bfr, acc[c], 0, 0, 0);
      }
    }

    __syncthreads();  // previous tile's clds readers done
    const int m0 = wave * 16 + kq * 4;
#pragma unroll
    for (int c = 0; c < 8; ++c) {
      int col = c * 16 + (lane & 15);
#pragma unroll
      for (int r = 0; r < 4; ++r) clds[(m0 + r) * 136 + col] = f2bf(acc[c][r]);
    }
    __syncthreads();
    // coalesced store: 64 rows x 16 int4
#pragma unroll
    for (int i = 0; i < 4; ++i) {
      int idx = t + 256 * i;
      int row = idx >> 4, piece = idx & 15;
      int grow = tile * 64 + row;
      if (grow < N)
        ((int4*)XW)[(size_t)tile * 1024 + idx] =
            *(const int4*)(clds + row * 136 + piece * 8);
    }
  }
}

// Aggregation: one node per wave. lane = e*16+c (e: edge slot 0..3, c: 16B piece).
// 16 lanes x uint4 = full 256B row per edge; 4 edges per gather instruction.
// Burst: 6 chunks (24 edges) of colw + gathers issued back-to-back -> ~96
// line-requests in flight per wave. Chunks past pdeg clamp to last entry, w=0.
__global__ __launch_bounds__(256, 6) void agg_kernel(const ushort* __restrict__ XW,
                                                     const uint* __restrict__ colw,
                                                     const int* __restrict__ rowptr,
                                                     const float* __restrict__ bias,
                                                     ushort* __restrict__ Y, int N) {
  const int lane = threadIdx.x & 63;
  const int node = blockIdx.x * 4 + (threadIdx.x >> 6);
  if (node >= N) return;
  const int e = lane >> 4, c = lane & 15;
  const int beg = rowptr[node];
  const int pdeg = rowptr[node + 1] - beg;  // multiple of 4, >= 4
  const int last = pdeg - 1;

  uint cw[6];
#pragma unroll
  for (int k = 0; k < 6; ++k) {
    int off = 4 * k + e;
    cw[k] = __builtin_nontemporal_load(colw + beg + (off < pdeg ? off : last));
  }
  uint4 gv[6];
#pragma unroll
  for (int k = 0; k < 6; ++k)
    gv[k] = *(const uint4*)(XW + ((size_t)cw_src(cw[k]) << 7) + c * 8);

  float acc[8];
#pragma unroll
  for (int i = 0; i < 8; ++i) acc[i] = 0.f;

#pragma unroll
  for (int k = 0; k < 6; ++k) {
    int off = 4 * k + e;
    float w = (off < pdeg) ? cw_w(cw[k]) : 0.f;
    uint4 v = gv[k];
    acc[0] += w * bflo(v.x); acc[1] += w * bfhi(v.x);
    acc[2] += w * bflo(v.y); acc[3] += w * bfhi(v.y);
    acc[4] += w * bflo(v.z); acc[5] += w * bfhi(v.z);
    acc[6] += w * bflo(v.w); acc[7] += w * bfhi(v.w);
  }
  // tail for deg > 23 (rare)
  for (int off = 24 + e; off < pdeg; off += 4) {
    uint u = __builtin_nontemporal_load(colw + beg + off);
    uint4 v = *(const uint4*)(XW + ((size_t)cw_src(u) << 7) + c * 8);
    float w = cw_w(u);
    acc[0] += w * bflo(v.x); acc[1] += w * bfhi(v.x);
    acc[2] += w * bflo(v.y); acc[3] += w * bfhi(v.y);
    acc[4] += w * bflo(v.z); acc[5] += w * bfhi(v.z);
    acc[6] += w * bflo(v.w); acc[7] += w * bfhi(v.w);
  }

#pragma unroll
  for (int i = 0; i < 8; ++i) {
    acc[i] += __shfl_xor(acc[i], 16, 64);
    acc[i] += __shfl_xor(acc[i], 32, 64);
  }
  if (e == 0) {
    float4 b0 = *(const float4*)(bias + c * 8);
    float4 b1 = *(const float4*)(bias + c * 8 + 4);
    uint4 pk;
    pk.x = (uint)f2bf(fmaxf(acc[0] + b0.x, 0.f)) | ((uint)f2bf(fmaxf(acc[1] + b0.y, 0.f)) << 16);
    pk.y = (uint)f2bf(fmaxf(acc[2] + b0.z, 0.f)) | ((uint)f2bf(fmaxf(acc[3] + b0.w, 0.f)) << 16);
    pk.z = (uint)f2bf(fmaxf(acc[4] + b1.x, 0.f)) | ((uint)f2bf(fmaxf(acc[5] + b1.y, 0.f)) << 16);
    pk.w = (uint)f2bf(fmaxf(acc[6] + b1.z, 0.f)) | ((uint)f2bf(fmaxf(acc[7] + b1.w, 0.f)) << 16);
    *(uint4*)(Y + (size_t)node * HDIM + c * 8) = pk;
  }
}

// ---------------- pooling + head ----------------

__global__ __launch_bounds__(256) void pool_partial(const ushort* __restrict__ x,
                                                    const int* __restrict__ batch,
                                                    float* __restrict__ pooled,
                                                    int* __restrict__ gcnt, int N) {
  const int g = blockIdx.x, s = blockIdx.y;  // gridDim.y = 8 splits
  const int t = threadIdx.x;
  __shared__ int range[2];
  __shared__ float sums[256];
  if (t < 2) {
    int target = g + t;
    int lo = 0, hi = N;
    while (lo < hi) {
      int mid = (lo + hi) >> 1;
      if (batch[mid] < target) lo = mid + 1;
      else hi = mid;
    }
    range[t] = lo;
  }
  __syncthreads();
  int beg = range[0], end = range[1];
  if (s == 0 && t == 0) gcnt[g] = end - beg;
  int col = t & 127, half = t >> 7;
  float acc = 0.f;
  for (int n = beg + s * 2 + half; n < end; n += 16) {
    acc += __uint_as_float(((uint)x[(size_t)n * HDIM + col]) << 16);
  }
  sums[t] = acc;
  __syncthreads();
  if (t < 128) atomicAdd(&pooled[g * HDIM + t], sums[t] + sums[t + 128]);
}

__global__ __launch_bounds__(256) void out_final(const float* __restrict__ pooled,
                                                 const int* __restrict__ gcnt,
                                                 const float* __restrict__ W_out,
                                                 const float* __restrict__ b_out,
                                                 float* __restrict__ out, int G, int C) {
  int i = blockIdx.x * 256 + threadIdx.x;
  if (i >= G * C) return;
  int g = i / C, c = i - g * C;
  float inv = 1.f / (float)max(gcnt[g], 1);
  const float* pg = pooled + g * HDIM;
  float o = 0.f;
  for (int h = 0; h < HDIM; ++h) o += pg[h] * W_out[h * C + c];
  out[i] = b_out[c] + o * inv;
}

// ---------------- host ----------------

extern "C" void kernel_launch(void* const* d_in, const int* in_sizes, int n_in,
                              void* d_out, int out_size, void* d_ws, size_t ws_size,
                              hipStream_t stream) {
  (void)n_in;
  (void)ws_size;
  const float* x = (const float*)d_in[0];
  const int* ei = (const int*)d_in[1];
  const int* batch = (const int*)d_in[2];
  const float* Ws = (const float*)d_in[4];
  const float* bs = (const float*)d_in[5];
  const float* W_out = (const float*)d_in[6];
  const float* b_out = (const float*)d_in[7];
  float* out = (float*)d_out;

  const int N = in_sizes[0] / HDIM;
  const int E = in_sizes[1] / 2;
  const int L = in_sizes[5] / HDIM;
  const int C = in_sizes[7];
  const int G = out_size / C;

  char* p = (char*)d_ws;
  auto carve = [&](size_t bytes) {
    char* r = p;
    p += (bytes + 255) & ~(size_t)255;
    return r;
  };
  int* cnt = (int*)carve((size_t)N * 4);
  float* dis = (float*)carve((size_t)N * 4);
  int* rowptr = (int*)carve((size_t)(N + 1) * 4);
  int* cursor = (int*)carve((size_t)N * 4);
  int* bsum = (int*)carve(4096);
  uint* colw = (uint*)carve(((size_t)E + 4 * (size_t)N + 64) * 4);
  ushort* Wsw = (ushort*)carve((size_t)L * HDIM * HDIM * 2);
  ushort* xw = (ushort*)carve((size_t)N * HDIM * 2);
  ushort* y0 = (ushort*)carve((size_t)N * HDIM * 2);
  ushort* y1 = (ushort*)carve((size_t)N * HDIM * 2);
  float* pooled = (float*)carve((size_t)G * HDIM * 4 + (size_t)G * 4);
  int* gcnt = (int*)(pooled + (size_t)G * HDIM);

  hipMemsetAsync(cnt, 0, (size_t)N * 4, stream);
  hipMemsetAsync(pooled, 0, (size_t)G * HDIM * 4 + (size_t)G * 4, stream);

  count_kernel<<<(E + 255) / 256, 256, 0, stream>>>(ei, cnt, E);
  dis_kernel<<<(N + 255) / 256, 256, 0, stream>>>(cnt, dis, N);
  int nb = (N + 1 + 1023) / 1024;
  scan1<<<nb, 256, 0, stream>>>(cnt, bsum, N);
  scan2<<<1, 256, 0, stream>>>(bsum, nb);
  scan3<<<nb, 256, 0, stream>>>(cnt, bsum, rowptr, cursor, N);
  fill_csr<<<(E + N + 255) / 256, 256, 0, stream>>>(ei, dis, cursor, colw, E, N);
  pad_csr<<<(N + 255) / 256, 256, 0, stream>>>(cnt, rowptr, colw, N);
  swz_w<<<(L * HDIM * HDIM + 255) / 256, 256, 0, stream>>>(Ws, Wsw, L * HDIM * HDIM);

  const int ntiles = (N + 63) / 64;
  const int gb = 768;  // persistent: 3 blocks/CU (49.4 KB LDS)
  gemm_kernel<true><<<gb, 256, 0, stream>>>(x, Wsw, xw, N, ntiles);
  agg_kernel<<<(N + 3) / 4, 256, 0, stream>>>(xw, colw, rowptr, bs, y0, N);
  ushort* xc = y0;
  ushort* xn = y1;
  for (int l = 1; l < L; ++l) {
    gemm_kernel<false><<<gb, 256, 0, stream>>>(xc, Wsw + (size_t)l * HDIM * HDIM, xw, N, ntiles);
    agg_kernel<<<(N + 3) / 4, 256, 0, stream>>>(xw, colw, rowptr, bs + (size_t)l * HDIM, xn, N);
    ushort* tmp = xc;
    xc = xn;
    xn = tmp;
  }
  pool_partial<<<dim3(G, 8), 256, 0, stream>>>(xc, batch, pooled, gcnt, N);
  out_final<<<(G * C + 255) / 256, 256, 0, stream>>>(pooled, gcnt, W_out, b_out, out, G, C);
}